// Round 1
// baseline (349.951 us; speedup 1.0000x reference)
//
#include <hip/hip_runtime.h>
#include <hip/hip_bf16.h>

// ---------------------------------------------------------------------------
// AttentionLayer: out = quirky_softmax(mask * (Q K^T)) @ V
//   Q = x Wq + bq ; K = x Wk + bk ; V = x Wv + bv
//   denom[j] = sum_k exp(mask[j,k]*S[j,k])  (row sums)
//   softmax[i,j] = E[i,j] / denom[j]        (column-indexed denom!)
//   => out = E @ (V scaled per-row by 1/denom)
// All heavy GEMMs in bf16 MFMA (16x16x32), fp32 accumulate.
// ---------------------------------------------------------------------------

#define N_TOK 4096
#define D_DIM 1024

typedef __bf16 bf16x8 __attribute__((ext_vector_type(8)));
typedef __bf16 bf16x4 __attribute__((ext_vector_type(4)));
typedef float  f32x4  __attribute__((ext_vector_type(4)));

typedef const __attribute__((address_space(1))) char g_char;
typedef __attribute__((address_space(3))) char lds_char;

// ---------------------------------------------------------------------------
// fp32 -> bf16 elementwise convert (vectorized x4)
// ---------------------------------------------------------------------------
__global__ void cvt_f32_to_bf16(const float* __restrict__ in,
                                __bf16* __restrict__ out, int n) {
    int i = (blockIdx.x * 256 + threadIdx.x) * 4;
    if (i + 3 < n) {
        float4 v = *(const float4*)(in + i);
        bf16x4 o;
        o.x = (__bf16)v.x; o.y = (__bf16)v.y;
        o.z = (__bf16)v.z; o.w = (__bf16)v.w;
        *(bf16x4*)(out + i) = o;
    }
}

// ---------------------------------------------------------------------------
// Transpose 1024x1024 fp32 -> bf16 [C][R] (for W matrices: [in][out] -> [out][in])
// ---------------------------------------------------------------------------
__global__ void transpose_w(const float* __restrict__ in, __bf16* __restrict__ outT) {
    __shared__ float t[64][65];
    const int c0 = blockIdx.x * 64, r0 = blockIdx.y * 64;
    const int tid = threadIdx.x;
#pragma unroll
    for (int k = 0; k < 16; k++) {
        int lin = tid + k * 256;
        int r = lin >> 6, c = lin & 63;
        t[r][c] = in[(size_t)(r0 + r) * 1024 + c0 + c];
    }
    __syncthreads();
#pragma unroll
    for (int k = 0; k < 16; k++) {
        int lin = tid + k * 256;
        int c = lin >> 6, r = lin & 63;
        outT[(size_t)(c0 + c) * 1024 + r0 + r] = (__bf16)t[r][c];
    }
}

// ---------------------------------------------------------------------------
// Row sums of E (bf16 [4096][4096]) -> denom fp32 [4096]
// ---------------------------------------------------------------------------
__global__ void rowsum_kernel(const __bf16* __restrict__ E, float* __restrict__ denom) {
    const int row = blockIdx.x;
    const int tid = threadIdx.x;
    const __bf16* p = E + (size_t)row * N_TOK + tid * 16;
    bf16x8 v0 = *(const bf16x8*)p;
    bf16x8 v1 = *(const bf16x8*)(p + 8);
    float s = 0.f;
#pragma unroll
    for (int i = 0; i < 8; i++) s += (float)v0[i] + (float)v1[i];
#pragma unroll
    for (int off = 32; off > 0; off >>= 1) s += __shfl_down(s, off, 64);
    __shared__ float partial[4];
    if ((tid & 63) == 0) partial[tid >> 6] = s;
    __syncthreads();
    if (tid == 0) denom[row] = partial[0] + partial[1] + partial[2] + partial[3];
}

// ---------------------------------------------------------------------------
// VsT[d][j] = bf16( V[j][d] / denom[j] )   V: bf16 [4096][1024] -> VsT [1024][4096]
// ---------------------------------------------------------------------------
__global__ void scale_transpose(const __bf16* __restrict__ V,
                                const float* __restrict__ denom,
                                __bf16* __restrict__ VT) {
    __shared__ float t[64][65];
    __shared__ float rd[64];
    const int d0 = blockIdx.x * 64, j0 = blockIdx.y * 64;
    const int tid = threadIdx.x;
    if (tid < 64) rd[tid] = 1.0f / denom[j0 + tid];
    __syncthreads();
#pragma unroll
    for (int k = 0; k < 16; k++) {
        int lin = tid + k * 256;
        int j = lin >> 6, d = lin & 63;
        t[j][d] = (float)V[(size_t)(j0 + j) * D_DIM + d0 + d] * rd[j];
    }
    __syncthreads();
#pragma unroll
    for (int k = 0; k < 16; k++) {
        int lin = tid + k * 256;
        int d = lin >> 6, j = lin & 63;
        VT[(size_t)(d0 + d) * N_TOK + j0 + j] = (__bf16)t[j][d];
    }
}

// ---------------------------------------------------------------------------
// NT GEMM: C[M][Nn] = A[M][K] * B[Nn][K]^T  (both row-major, bf16, fp32 acc)
// 128x128 block tile, BK=32, 4 waves each computing 64x64 (4x4 MFMA frags).
// EPI 0: C = acc + bias[col] -> bf16
// EPI 1: C = exp(mask[idx] * acc) -> bf16
// EPI 2: C = acc -> fp32
// ---------------------------------------------------------------------------
template <int EPI>
__global__ __launch_bounds__(256, 2)
void gemm_nt(const __bf16* __restrict__ A, const __bf16* __restrict__ B,
             int M, int Nn, int K,
             const float* __restrict__ bias,
             const float* __restrict__ mask,
             __bf16* __restrict__ Cb, float* __restrict__ Cf) {
    __shared__ __bf16 lA[128 * 32];
    __shared__ __bf16 lB[128 * 32];

    const int tid  = threadIdx.x;
    const int wave = tid >> 6;
    const int lane = tid & 63;
    const int quad = lane >> 4;
    const int l16  = lane & 15;
    const int m0 = blockIdx.y * 128;
    const int n0 = blockIdx.x * 128;
    const int wr = (wave >> 1) * 64;   // wave row offset in tile
    const int wc = (wave & 1) * 64;    // wave col offset in tile

    // ---- global->LDS staging addresses -----------------------------------
    // Tile is 128 rows x 32 cols bf16 = 64 B/row, 8192 B. Each thread copies
    // 16 B twice (c=0,1). Linear byte offset o = c*4096 + tid*16 maps to
    // row = o/64, byte-in-row = o%64. LDS dest must be base + lane*16 with
    // wave-uniform base (global_load_lds constraint).
    const size_t ldab = (size_t)K * 2;        // row stride in bytes
    const int o = tid * 16;
    const char* gA = (const char*)A + (size_t)(m0 + (o >> 6)) * ldab + (o & 63);
    const char* gB = (const char*)B + (size_t)(n0 + (o >> 6)) * ldab + (o & 63);
    const size_t cstep = (size_t)64 * ldab;   // c=1: +64 rows

    lds_char* lAp = (lds_char*)(void*)lA + wave * 1024;
    lds_char* lBp = (lds_char*)(void*)lB + wave * 1024;

    f32x4 acc[4][4];
#pragma unroll
    for (int i = 0; i < 4; i++)
#pragma unroll
        for (int j = 0; j < 4; j++) acc[i][j] = (f32x4){0.f, 0.f, 0.f, 0.f};

    for (int kt = 0; kt < K; kt += 32) {
        __builtin_amdgcn_global_load_lds((g_char*)gA,           lAp,        16, 0, 0);
        __builtin_amdgcn_global_load_lds((g_char*)(gA + cstep), lAp + 4096, 16, 0, 0);
        __builtin_amdgcn_global_load_lds((g_char*)gB,           lBp,        16, 0, 0);
        __builtin_amdgcn_global_load_lds((g_char*)(gB + cstep), lBp + 4096, 16, 0, 0);
        gA += 64;  // next BK=32 chunk (64 B)
        gB += 64;
        __syncthreads();   // drains vmcnt (global_load_lds) + joins waves

        bf16x8 af[4], bfr[4];
#pragma unroll
        for (int i = 0; i < 4; i++)
            af[i] = *(const bf16x8*)&lA[(wr + i * 16 + l16) * 32 + quad * 8];
#pragma unroll
        for (int i = 0; i < 4; i++)
            bfr[i] = *(const bf16x8*)&lB[(wc + i * 16 + l16) * 32 + quad * 8];

#pragma unroll
        for (int i = 0; i < 4; i++)
#pragma unroll
            for (int j = 0; j < 4; j++)
                acc[i][j] = __builtin_amdgcn_mfma_f32_16x16x32_bf16(
                    af[i], bfr[j], acc[i][j], 0, 0, 0);
        __syncthreads();
    }

    // ---- epilogue: C/D layout col=lane&15, row=quad*4+reg ----------------
#pragma unroll
    for (int i = 0; i < 4; i++) {
#pragma unroll
        for (int j = 0; j < 4; j++) {
            const int col   = n0 + wc + j * 16 + l16;
            const int rbase = m0 + wr + i * 16 + quad * 4;
            f32x4 v = acc[i][j];
            if (EPI == 0) {
                const float bb = bias[col];
#pragma unroll
                for (int r = 0; r < 4; r++)
                    Cb[(size_t)(rbase + r) * Nn + col] = (__bf16)(v[r] + bb);
            } else if (EPI == 1) {
#pragma unroll
                for (int r = 0; r < 4; r++) {
                    size_t idx = (size_t)(rbase + r) * Nn + col;
                    Cb[idx] = (__bf16)__expf(mask[idx] * v[r]);
                }
            } else {
#pragma unroll
                for (int r = 0; r < 4; r++)
                    Cf[(size_t)(rbase + r) * Nn + col] = v[r];
            }
        }
    }
}

// ---------------------------------------------------------------------------
extern "C" void kernel_launch(void* const* d_in, const int* in_sizes, int n_in,
                              void* d_out, int out_size, void* d_ws, size_t ws_size,
                              hipStream_t stream) {
    const float* x    = (const float*)d_in[0];   // [4096][1024]
    const float* mask = (const float*)d_in[1];   // [4096][4096]
    const float* Wq   = (const float*)d_in[2];
    const float* bq   = (const float*)d_in[3];
    const float* Wk   = (const float*)d_in[4];
    const float* bk   = (const float*)d_in[5];
    const float* Wv   = (const float*)d_in[6];
    const float* bv   = (const float*)d_in[7];
    float* out = (float*)d_out;                  // [4096][1024] fp32
    char* ws = (char*)d_ws;

    const size_t MB = 1024 * 1024;
    __bf16* xb   = (__bf16*)(ws + 0 * MB);    // 8 MB  [4096][1024]
    __bf16* WqT  = (__bf16*)(ws + 8 * MB);    // 2 MB  [1024 out][1024 in]
    __bf16* WkT  = (__bf16*)(ws + 10 * MB);   // 2 MB
    __bf16* WvT  = (__bf16*)(ws + 12 * MB);   // 2 MB
    __bf16* Qb   = (__bf16*)(ws + 14 * MB);   // 8 MB  [4096][1024]
    __bf16* Kb   = (__bf16*)(ws + 22 * MB);   // 8 MB
    __bf16* Vb   = (__bf16*)(ws + 30 * MB);   // 8 MB
    __bf16* Eb   = (__bf16*)(ws + 38 * MB);   // 32 MB [4096][4096]
    float*  denom = (float*)(ws + 70 * MB);   // 16 KB
    __bf16* VsT  = xb;                        // reuse xb (dead after projections)

    // x -> bf16
    cvt_f32_to_bf16<<<4096, 256, 0, stream>>>(x, xb, N_TOK * D_DIM);
    // W -> bf16 transposed [out][in]
    transpose_w<<<dim3(16, 16), 256, 0, stream>>>(Wq, WqT);
    transpose_w<<<dim3(16, 16), 256, 0, stream>>>(Wk, WkT);
    transpose_w<<<dim3(16, 16), 256, 0, stream>>>(Wv, WvT);

    // Projections: [4096][1024] = xb [4096][1024] @ WT[1024][1024]^T + b
    gemm_nt<0><<<dim3(8, 32), 256, 0, stream>>>(xb, WqT, N_TOK, D_DIM, D_DIM,
                                                bq, nullptr, Qb, nullptr);
    gemm_nt<0><<<dim3(8, 32), 256, 0, stream>>>(xb, WkT, N_TOK, D_DIM, D_DIM,
                                                bk, nullptr, Kb, nullptr);
    gemm_nt<0><<<dim3(8, 32), 256, 0, stream>>>(xb, WvT, N_TOK, D_DIM, D_DIM,
                                                bv, nullptr, Vb, nullptr);

    // E = exp(mask * (Q K^T))  -> bf16 [4096][4096]
    gemm_nt<1><<<dim3(32, 32), 256, 0, stream>>>(Qb, Kb, N_TOK, N_TOK, D_DIM,
                                                 nullptr, mask, Eb, nullptr);

    // denom[j] = sum_k E[j][k]
    rowsum_kernel<<<N_TOK, 256, 0, stream>>>(Eb, denom);

    // VsT[d][j] = V[j][d] / denom[j]
    scale_transpose<<<dim3(16, 64), 256, 0, stream>>>(Vb, denom, VsT);

    // out = E @ Vs   (NT with B = VsT [1024][4096])
    gemm_nt<2><<<dim3(8, 32), 256, 0, stream>>>(Eb, VsT, N_TOK, D_DIM, N_TOK,
                                                nullptr, nullptr, nullptr, out);
}

// Round 2
// 289.309 us; speedup vs baseline: 1.2096x; 1.2096x over previous
//
#include <hip/hip_runtime.h>
#include <hip/hip_bf16.h>

// ---------------------------------------------------------------------------
// AttentionLayer: out = quirky_softmax(mask * (Q K^T)) @ V
//   denom[j] = sum_k exp(mask[j,k]*S[j,k])  (row sums)
//   softmax[i,j] = E[i,j] / denom[j]        (column-indexed denom!)
//   => out = E @ (V scaled per-row by 1/denom)
// R1: fused QKV projection (3 blocks/CU), split-K=2 out-GEMM (2 blocks/CU).
// ---------------------------------------------------------------------------

#define N_TOK 4096
#define D_DIM 1024

typedef __bf16 bf16x8 __attribute__((ext_vector_type(8)));
typedef __bf16 bf16x4 __attribute__((ext_vector_type(4)));
typedef float  f32x4  __attribute__((ext_vector_type(4)));

typedef const __attribute__((address_space(1))) char g_char;
typedef __attribute__((address_space(3))) char lds_char;

// ---------------------------------------------------------------------------
__global__ void cvt_f32_to_bf16(const float* __restrict__ in,
                                __bf16* __restrict__ out, int n) {
    int i = (blockIdx.x * 256 + threadIdx.x) * 4;
    if (i + 3 < n) {
        float4 v = *(const float4*)(in + i);
        bf16x4 o;
        o.x = (__bf16)v.x; o.y = (__bf16)v.y;
        o.z = (__bf16)v.z; o.w = (__bf16)v.w;
        *(bf16x4*)(out + i) = o;
    }
}

// ---------------------------------------------------------------------------
// Transpose 1024x1024 fp32 -> bf16 [out][in]
// ---------------------------------------------------------------------------
__global__ void transpose_w(const float* __restrict__ in, __bf16* __restrict__ outT) {
    __shared__ float t[64][65];
    const int c0 = blockIdx.x * 64, r0 = blockIdx.y * 64;
    const int tid = threadIdx.x;
#pragma unroll
    for (int k = 0; k < 16; k++) {
        int lin = tid + k * 256;
        int r = lin >> 6, c = lin & 63;
        t[r][c] = in[(size_t)(r0 + r) * 1024 + c0 + c];
    }
    __syncthreads();
#pragma unroll
    for (int k = 0; k < 16; k++) {
        int lin = tid + k * 256;
        int c = lin >> 6, r = lin & 63;
        outT[(size_t)(c0 + c) * 1024 + r0 + r] = (__bf16)t[r][c];
    }
}

__global__ void concat_bias(const float* __restrict__ bq, const float* __restrict__ bk,
                            const float* __restrict__ bv, float* __restrict__ bcat) {
    int i = blockIdx.x * 256 + threadIdx.x;
    if (i < 1024) bcat[i] = bq[i];
    else if (i < 2048) bcat[i] = bk[i - 1024];
    else if (i < 3072) bcat[i] = bv[i - 2048];
}

// ---------------------------------------------------------------------------
__global__ void rowsum_kernel(const __bf16* __restrict__ E, float* __restrict__ denom) {
    const int row = blockIdx.x;
    const int tid = threadIdx.x;
    const __bf16* p = E + (size_t)row * N_TOK + tid * 16;
    bf16x8 v0 = *(const bf16x8*)p;
    bf16x8 v1 = *(const bf16x8*)(p + 8);
    float s = 0.f;
#pragma unroll
    for (int i = 0; i < 8; i++) s += (float)v0[i] + (float)v1[i];
#pragma unroll
    for (int off = 32; off > 0; off >>= 1) s += __shfl_down(s, off, 64);
    __shared__ float partial[4];
    if ((tid & 63) == 0) partial[tid >> 6] = s;
    __syncthreads();
    if (tid == 0) denom[row] = partial[0] + partial[1] + partial[2] + partial[3];
}

// ---------------------------------------------------------------------------
// VsT[d][j] = bf16( V[j][d] / denom[j] ), V row stride ldv
// ---------------------------------------------------------------------------
__global__ void scale_transpose(const __bf16* __restrict__ V, int ldv,
                                const float* __restrict__ denom,
                                __bf16* __restrict__ VT) {
    __shared__ float t[64][65];
    __shared__ float rd[64];
    const int d0 = blockIdx.x * 64, j0 = blockIdx.y * 64;
    const int tid = threadIdx.x;
    if (tid < 64) rd[tid] = 1.0f / denom[j0 + tid];
    __syncthreads();
#pragma unroll
    for (int k = 0; k < 16; k++) {
        int lin = tid + k * 256;
        int j = lin >> 6, d = lin & 63;
        t[j][d] = (float)V[(size_t)(j0 + j) * ldv + d0 + d] * rd[j];
    }
    __syncthreads();
#pragma unroll
    for (int k = 0; k < 16; k++) {
        int lin = tid + k * 256;
        int d = lin >> 6, j = lin & 63;
        VT[(size_t)(d0 + d) * N_TOK + j0 + j] = (__bf16)t[j][d];
    }
}

__global__ void add_inplace(float* __restrict__ out, const float* __restrict__ p) {
    int i = (blockIdx.x * 256 + threadIdx.x) * 4;
    float4 a = *(const float4*)(out + i);
    float4 b = *(const float4*)(p + i);
    a.x += b.x; a.y += b.y; a.z += b.z; a.w += b.w;
    *(float4*)(out + i) = a;
}

// ---------------------------------------------------------------------------
// NT GEMM: C[M][Nn] = A * B^T, bf16 in, fp32 acc. Strided rows (lda/ldb/ldc
// in elements). Split-K via gridDim.z (each z does Kz contiguous K-elems;
// z=0 writes Cf0, z=1 writes Cf1 for EPI 2).
// EPI 0: Cb = bf16(acc + bias[col])
// EPI 1: Cb = bf16(exp(mask[r*ldc+col] * acc))
// EPI 2: Cf = acc (fp32)
// ---------------------------------------------------------------------------
template <int EPI>
__global__ __launch_bounds__(256, 2)
void gemm_nt(const __bf16* __restrict__ A, const __bf16* __restrict__ B,
             int lda, int ldb, int ldc, int Kz,
             const float* __restrict__ bias,
             const float* __restrict__ mask,
             __bf16* __restrict__ Cb,
             float* __restrict__ Cf0, float* __restrict__ Cf1) {
    __shared__ __bf16 lA[128 * 32];
    __shared__ __bf16 lB[128 * 32];

    const int tid  = threadIdx.x;
    const int wave = tid >> 6;
    const int lane = tid & 63;
    const int quad = lane >> 4;
    const int l16  = lane & 15;
    const int m0 = blockIdx.y * 128;
    const int n0 = blockIdx.x * 128;
    const int wr = (wave >> 1) * 64;
    const int wc = (wave & 1) * 64;

    // global->LDS staging: tile 128 rows x 64 B; thread copies 16 B at
    // linear offset o=tid*16 (row o/64, byte o%64) plus +64 rows for c=1.
    const size_t lda_b = (size_t)lda * 2;
    const size_t ldb_b = (size_t)ldb * 2;
    const int o = tid * 16;
    const size_t koff = (size_t)blockIdx.z * Kz * 2;   // split-K byte offset
    const char* gA = (const char*)A + (size_t)(m0 + (o >> 6)) * lda_b + (o & 63) + koff;
    const char* gB = (const char*)B + (size_t)(n0 + (o >> 6)) * ldb_b + (o & 63) + koff;
    const size_t cstepA = (size_t)64 * lda_b;
    const size_t cstepB = (size_t)64 * ldb_b;

    lds_char* lAp = (lds_char*)(void*)lA + wave * 1024;
    lds_char* lBp = (lds_char*)(void*)lB + wave * 1024;

    f32x4 acc[4][4];
#pragma unroll
    for (int i = 0; i < 4; i++)
#pragma unroll
        for (int j = 0; j < 4; j++) acc[i][j] = (f32x4){0.f, 0.f, 0.f, 0.f};

    for (int kt = 0; kt < Kz; kt += 32) {
        __builtin_amdgcn_global_load_lds((g_char*)gA,            lAp,        16, 0, 0);
        __builtin_amdgcn_global_load_lds((g_char*)(gA + cstepA), lAp + 4096, 16, 0, 0);
        __builtin_amdgcn_global_load_lds((g_char*)gB,            lBp,        16, 0, 0);
        __builtin_amdgcn_global_load_lds((g_char*)(gB + cstepB), lBp + 4096, 16, 0, 0);
        gA += 64;
        gB += 64;
        __syncthreads();

        bf16x8 af[4], bfr[4];
#pragma unroll
        for (int i = 0; i < 4; i++)
            af[i] = *(const bf16x8*)&lA[(wr + i * 16 + l16) * 32 + quad * 8];
#pragma unroll
        for (int i = 0; i < 4; i++)
            bfr[i] = *(const bf16x8*)&lB[(wc + i * 16 + l16) * 32 + quad * 8];

#pragma unroll
        for (int i = 0; i < 4; i++)
#pragma unroll
            for (int j = 0; j < 4; j++)
                acc[i][j] = __builtin_amdgcn_mfma_f32_16x16x32_bf16(
                    af[i], bfr[j], acc[i][j], 0, 0, 0);
        __syncthreads();
    }

    float* Cf = (blockIdx.z == 0) ? Cf0 : Cf1;

    // epilogue: C/D layout col=lane&15, row=quad*4+reg
#pragma unroll
    for (int i = 0; i < 4; i++) {
#pragma unroll
        for (int j = 0; j < 4; j++) {
            const int col   = n0 + wc + j * 16 + l16;
            const int rbase = m0 + wr + i * 16 + quad * 4;
            f32x4 v = acc[i][j];
            if (EPI == 0) {
                const float bb = bias[col];
#pragma unroll
                for (int r = 0; r < 4; r++)
                    Cb[(size_t)(rbase + r) * ldc + col] = (__bf16)(v[r] + bb);
            } else if (EPI == 1) {
#pragma unroll
                for (int r = 0; r < 4; r++) {
                    size_t idx = (size_t)(rbase + r) * ldc + col;
                    Cb[idx] = (__bf16)__expf(mask[idx] * v[r]);
                }
            } else {
#pragma unroll
                for (int r = 0; r < 4; r++)
                    Cf[(size_t)(rbase + r) * ldc + col] = v[r];
            }
        }
    }
}

// ---------------------------------------------------------------------------
extern "C" void kernel_launch(void* const* d_in, const int* in_sizes, int n_in,
                              void* d_out, int out_size, void* d_ws, size_t ws_size,
                              hipStream_t stream) {
    const float* x    = (const float*)d_in[0];
    const float* mask = (const float*)d_in[1];
    const float* Wq   = (const float*)d_in[2];
    const float* bq   = (const float*)d_in[3];
    const float* Wk   = (const float*)d_in[4];
    const float* bk   = (const float*)d_in[5];
    const float* Wv   = (const float*)d_in[6];
    const float* bv   = (const float*)d_in[7];
    float* out = (float*)d_out;
    char* ws = (char*)d_ws;

    const size_t MB = 1024 * 1024;
    __bf16* Eb    = (__bf16*)(ws + 0 * MB);    // 32 MB [4096][4096]
    __bf16* QKVb  = (__bf16*)(ws + 32 * MB);   // 24 MB [4096][3072]
    float*  P1    = (float*)(ws + 32 * MB);    // 16 MB fp32 partial (reuses dead QKVb)
    __bf16* xb    = (__bf16*)(ws + 56 * MB);   // 8 MB [4096][1024]
    __bf16* VsT   = xb;                        // 8 MB (reuses dead xb)
    __bf16* WcatT = (__bf16*)(ws + 64 * MB);   // 6 MB [3072][1024]
    float*  bcat  = (float*)(ws + 70 * MB);    // 12 KB
    float*  denom = (float*)(ws + 70 * MB + 64 * 1024);  // 16 KB

    // ---- prep ----
    cvt_f32_to_bf16<<<4096, 256, 0, stream>>>(x, xb, N_TOK * D_DIM);
    transpose_w<<<dim3(16, 16), 256, 0, stream>>>(Wq, WcatT);
    transpose_w<<<dim3(16, 16), 256, 0, stream>>>(Wk, WcatT + 1024 * 1024);
    transpose_w<<<dim3(16, 16), 256, 0, stream>>>(Wv, WcatT + 2048 * 1024);
    concat_bias<<<12, 256, 0, stream>>>(bq, bk, bv, bcat);

    // ---- fused QKV projection: QKV[4096][3072] = xb @ Wcat^T + bcat ----
    gemm_nt<0><<<dim3(24, 32, 1), 256, 0, stream>>>(
        xb, WcatT, D_DIM, D_DIM, 3 * D_DIM, D_DIM,
        bcat, nullptr, QKVb, nullptr, nullptr);

    // ---- E = exp(mask * (Q K^T)) ----
    const __bf16* Qb = QKVb;
    const __bf16* Kb = QKVb + D_DIM;
    gemm_nt<1><<<dim3(32, 32, 1), 256, 0, stream>>>(
        Qb, Kb, 3 * D_DIM, 3 * D_DIM, N_TOK, D_DIM,
        nullptr, mask, Eb, nullptr, nullptr);

    // ---- denom[j] = sum_k E[j][k] ----
    rowsum_kernel<<<N_TOK, 256, 0, stream>>>(Eb, denom);

    // ---- VsT[d][j] = V[j][d]/denom[j] (V strided in QKV buffer) ----
    scale_transpose<<<dim3(16, 64), 256, 0, stream>>>(QKVb + 2048, 3 * D_DIM, denom, VsT);

    // ---- out = E @ Vs, split-K=2: z=0 -> out, z=1 -> P1 ----
    gemm_nt<2><<<dim3(8, 32, 2), 256, 0, stream>>>(
        Eb, VsT, N_TOK, N_TOK, D_DIM, N_TOK / 2,
        nullptr, nullptr, nullptr, out, P1);

    // ---- out += P1 ----
    add_inplace<<<4096, 256, 0, stream>>>(out, P1);
}

// Round 3
// 261.347 us; speedup vs baseline: 1.3390x; 1.1070x over previous
//
#include <hip/hip_runtime.h>
#include <hip/hip_bf16.h>

// ---------------------------------------------------------------------------
// AttentionLayer: out = quirky_softmax(mask * (Q K^T)) @ V
//   denom[j] = sum_k exp(mask[j,k]*S[j,k])  (row sums)
//   softmax[i,j] = E[i,j] / denom[j]        (column-indexed denom!)
//   => out = E @ (V scaled per-row by 1/denom)
// R2: BK=64 + XOR-swizzled LDS (kills bank conflicts, halves barriers),
//     rowsum fused into E-GEMM epilogue (atomics), out-GEMM 128x64 tiles
//     (no split-K, no add pass), merged prep kernels.
// ---------------------------------------------------------------------------

#define N_TOK 4096
#define D_DIM 1024

typedef __bf16 bf16x8 __attribute__((ext_vector_type(8)));
typedef __bf16 bf16x4 __attribute__((ext_vector_type(4)));
typedef float  f32x4  __attribute__((ext_vector_type(4)));

typedef const __attribute__((address_space(1))) char g_char;
typedef __attribute__((address_space(3))) char lds_char;

// ---------------------------------------------------------------------------
// fp32 -> bf16 convert (blocks 0..4095) + bias concat (blocks 4096..4107)
// ---------------------------------------------------------------------------
__global__ void cvt_and_bias(const float* __restrict__ x, __bf16* __restrict__ xb,
                             const float* __restrict__ bq, const float* __restrict__ bk,
                             const float* __restrict__ bv, float* __restrict__ bcat) {
    int b = blockIdx.x;
    if (b < 4096) {
        int i = (b * 256 + threadIdx.x) * 4;
        float4 v = *(const float4*)(x + i);
        bf16x4 o;
        o.x = (__bf16)v.x; o.y = (__bf16)v.y;
        o.z = (__bf16)v.z; o.w = (__bf16)v.w;
        *(bf16x4*)(xb + i) = o;
    } else {
        int i = (b - 4096) * 256 + threadIdx.x;
        if (i < 1024) bcat[i] = bq[i];
        else if (i < 2048) bcat[i] = bk[i - 1024];
        else if (i < 3072) bcat[i] = bv[i - 2048];
    }
}

// ---------------------------------------------------------------------------
// Transpose three 1024x1024 fp32 W -> bf16 [out][in], concatenated
// ---------------------------------------------------------------------------
__global__ void transpose_w3(const float* __restrict__ Wq, const float* __restrict__ Wk,
                             const float* __restrict__ Wv, __bf16* __restrict__ outT) {
    const float* in = (blockIdx.z == 0) ? Wq : (blockIdx.z == 1) ? Wk : Wv;
    __bf16* oT = outT + (size_t)blockIdx.z * 1024 * 1024;
    __shared__ float t[64][65];
    const int c0 = blockIdx.x * 64, r0 = blockIdx.y * 64;
    const int tid = threadIdx.x;
#pragma unroll
    for (int k = 0; k < 16; k++) {
        int lin = tid + k * 256;
        int r = lin >> 6, c = lin & 63;
        t[r][c] = in[(size_t)(r0 + r) * 1024 + c0 + c];
    }
    __syncthreads();
#pragma unroll
    for (int k = 0; k < 16; k++) {
        int lin = tid + k * 256;
        int c = lin >> 6, r = lin & 63;
        oT[(size_t)(c0 + c) * 1024 + r0 + r] = (__bf16)t[r][c];
    }
}

// ---------------------------------------------------------------------------
// VsT[d][j] = bf16( V[j][d] / denom[j] ), V row stride ldv
// ---------------------------------------------------------------------------
__global__ void scale_transpose(const __bf16* __restrict__ V, int ldv,
                                const float* __restrict__ denom,
                                __bf16* __restrict__ VT) {
    __shared__ float t[64][65];
    __shared__ float rd[64];
    const int d0 = blockIdx.x * 64, j0 = blockIdx.y * 64;
    const int tid = threadIdx.x;
    if (tid < 64) rd[tid] = 1.0f / denom[j0 + tid];
    __syncthreads();
#pragma unroll
    for (int k = 0; k < 16; k++) {
        int lin = tid + k * 256;
        int j = lin >> 6, d = lin & 63;
        t[j][d] = (float)V[(size_t)(j0 + j) * ldv + d0 + d] * rd[j];
    }
    __syncthreads();
#pragma unroll
    for (int k = 0; k < 16; k++) {
        int lin = tid + k * 256;
        int d = lin >> 6, j = lin & 63;
        VT[(size_t)(d0 + d) * N_TOK + j0 + j] = (__bf16)t[j][d];
    }
}

// ---------------------------------------------------------------------------
// NT GEMM: C[M][Nn] = A * B^T, bf16 in, fp32 acc, BK=64, 128xTN block tile.
// LDS layout XOR-swizzled: 16B chunk q of row r stored at position q^(r&7)
// (row = 128 B = 8 chunks). global_load_lds writes lane-contiguous, so the
// swizzle is applied on the global SOURCE address per thread; reads use the
// matching swizzled position -> uniform bank spread (no conflicts).
// EPI 0: Cb = bf16(acc + bias[col])
// EPI 1: Cb = bf16(exp(mask[idx]*acc)); denom[row] += rowsum (atomic)
// EPI 2: Cf = acc (fp32)
// ---------------------------------------------------------------------------
template <int EPI, int TN>
__global__ __launch_bounds__(256, 2)
void gemm_nt(const __bf16* __restrict__ A, const __bf16* __restrict__ B,
             int lda, int ldb, int ldc, int K,
             const float* __restrict__ bias,
             const float* __restrict__ mask,
             __bf16* __restrict__ Cb, float* __restrict__ Cf,
             float* __restrict__ denom) {
    constexpr int NF = TN / 32;            // B frags per wave = B staging passes
    __shared__ __bf16 lA[128 * 64];
    __shared__ __bf16 lB[TN * 64];

    const int tid  = threadIdx.x;
    const int wave = tid >> 6;
    const int lane = tid & 63;
    const int quad = lane >> 4;
    const int l16  = lane & 15;
    const int m0 = blockIdx.y * 128;
    const int n0 = blockIdx.x * TN;
    const int wr = (wave >> 1) * 64;       // wave row offset (0/64)
    const int wc = (wave & 1) * (TN / 2);  // wave col offset

    // ---- staging source addresses (swizzled) -----------------------------
    // LDS chunk p = c*256 + tid holds global chunk ((p&7)^((p>>3)&7)) of row
    // (p>>3). Since pass step = 32 rows (0 mod 8), swizzle is pass-invariant.
    const size_t lda_b = (size_t)lda * 2;
    const size_t ldb_b = (size_t)ldb * 2;
    const int tr = tid >> 3;                          // row 0..31
    const int ts = ((tid & 7) ^ (tr & 7)) * 16;       // swizzled source byte
    const char* gA = (const char*)A + (size_t)(m0 + tr) * lda_b + ts;
    const char* gB = (const char*)B + (size_t)(n0 + tr) * ldb_b + ts;
    const size_t pstepA = (size_t)32 * lda_b;
    const size_t pstepB = (size_t)32 * ldb_b;

    lds_char* lAp = (lds_char*)(void*)lA + wave * 1024;
    lds_char* lBp = (lds_char*)(void*)lB + wave * 1024;

    // ---- LDS read addresses (element index), per kstep -------------------
    // frag chunk in row = ks*4 + quad; swizzled pos = chunk ^ (row&7), row&7 = l16&7
    const int l7 = l16 & 7;
    const int rdA0 = ((wr + l16) * 128 + ((quad ^ l7) * 16)) >> 1;
    const int rdA1 = ((wr + l16) * 128 + (((4 + quad) ^ l7) * 16)) >> 1;
    const int rdB0 = ((wc + l16) * 128 + ((quad ^ l7) * 16)) >> 1;
    const int rdB1 = ((wc + l16) * 128 + (((4 + quad) ^ l7) * 16)) >> 1;

    f32x4 acc[4][NF];
#pragma unroll
    for (int i = 0; i < 4; i++)
#pragma unroll
        for (int j = 0; j < NF; j++) acc[i][j] = (f32x4){0.f, 0.f, 0.f, 0.f};

    for (int kt = 0; kt < K; kt += 64) {
#pragma unroll
        for (int c = 0; c < 4; c++)
            __builtin_amdgcn_global_load_lds((g_char*)(gA + c * pstepA),
                                             lAp + c * 4096, 16, 0, 0);
#pragma unroll
        for (int c = 0; c < NF; c++)
            __builtin_amdgcn_global_load_lds((g_char*)(gB + c * pstepB),
                                             lBp + c * 4096, 16, 0, 0);
        gA += 128;  // next BK=64 chunk
        gB += 128;
        __syncthreads();

        bf16x8 af[4], bfr[NF];
        // kstep 0
#pragma unroll
        for (int i = 0; i < 4; i++) af[i] = *(const bf16x8*)&lA[rdA0 + i * 1024];
#pragma unroll
        for (int j = 0; j < NF; j++) bfr[j] = *(const bf16x8*)&lB[rdB0 + j * 1024];
#pragma unroll
        for (int i = 0; i < 4; i++)
#pragma unroll
            for (int j = 0; j < NF; j++)
                acc[i][j] = __builtin_amdgcn_mfma_f32_16x16x32_bf16(
                    af[i], bfr[j], acc[i][j], 0, 0, 0);
        // kstep 1
#pragma unroll
        for (int i = 0; i < 4; i++) af[i] = *(const bf16x8*)&lA[rdA1 + i * 1024];
#pragma unroll
        for (int j = 0; j < NF; j++) bfr[j] = *(const bf16x8*)&lB[rdB1 + j * 1024];
#pragma unroll
        for (int i = 0; i < 4; i++)
#pragma unroll
            for (int j = 0; j < NF; j++)
                acc[i][j] = __builtin_amdgcn_mfma_f32_16x16x32_bf16(
                    af[i], bfr[j], acc[i][j], 0, 0, 0);
        __syncthreads();
    }

    // ---- epilogue: C/D layout col=lane&15, row=quad*4+reg ----------------
#pragma unroll
    for (int i = 0; i < 4; i++) {
        const int rbase = m0 + wr + i * 16 + quad * 4;
        f32x4 rs = (f32x4){0.f, 0.f, 0.f, 0.f};
#pragma unroll
        for (int j = 0; j < NF; j++) {
            const int col = n0 + wc + j * 16 + l16;
            f32x4 v = acc[i][j];
            if (EPI == 0) {
                const float bb = bias[col];
#pragma unroll
                for (int r = 0; r < 4; r++)
                    Cb[(size_t)(rbase + r) * ldc + col] = (__bf16)(v[r] + bb);
            } else if (EPI == 1) {
#pragma unroll
                for (int r = 0; r < 4; r++) {
                    size_t idx = (size_t)(rbase + r) * ldc + col;
                    __bf16 eb = (__bf16)__expf(mask[idx] * v[r]);
                    Cb[idx] = eb;
                    rs[r] += (float)eb;   // sum the bf16-rounded value
                }
            } else {
#pragma unroll
                for (int r = 0; r < 4; r++)
                    Cf[(size_t)(rbase + r) * ldc + col] = v[r];
            }
        }
        if (EPI == 1) {
            // reduce rs over the 16 lanes sharing this quad, then atomic
#pragma unroll
            for (int m = 1; m < 16; m <<= 1) {
#pragma unroll
                for (int r = 0; r < 4; r++) rs[r] += __shfl_xor(rs[r], m, 64);
            }
            if (l16 == 0) {
#pragma unroll
                for (int r = 0; r < 4; r++) atomicAdd(&denom[rbase + r], rs[r]);
            }
        }
    }
}

// ---------------------------------------------------------------------------
extern "C" void kernel_launch(void* const* d_in, const int* in_sizes, int n_in,
                              void* d_out, int out_size, void* d_ws, size_t ws_size,
                              hipStream_t stream) {
    const float* x    = (const float*)d_in[0];
    const float* mask = (const float*)d_in[1];
    const float* Wq   = (const float*)d_in[2];
    const float* bq   = (const float*)d_in[3];
    const float* Wk   = (const float*)d_in[4];
    const float* bk   = (const float*)d_in[5];
    const float* Wv   = (const float*)d_in[6];
    const float* bv   = (const float*)d_in[7];
    float* out = (float*)d_out;
    char* ws = (char*)d_ws;

    const size_t MB = 1024 * 1024;
    __bf16* Eb    = (__bf16*)(ws + 0 * MB);    // 32 MB [4096][4096]
    __bf16* QKVb  = (__bf16*)(ws + 32 * MB);   // 24 MB [4096][3072]
    __bf16* xb    = (__bf16*)(ws + 56 * MB);   // 8 MB [4096][1024]
    __bf16* VsT   = xb;                        // reuse (dead after QKV GEMM)
    __bf16* WcatT = (__bf16*)(ws + 64 * MB);   // 6 MB [3072][1024]
    float*  bcat  = (float*)(ws + 70 * MB);    // 12 KB
    float*  denom = (float*)(ws + 70 * MB + 64 * 1024);  // 16 KB

    // denom zero-init (workspace is poisoned each call)
    hipMemsetAsync(denom, 0, N_TOK * sizeof(float), stream);

    // ---- prep ----
    cvt_and_bias<<<4096 + 12, 256, 0, stream>>>(x, xb, bq, bk, bv, bcat);
    transpose_w3<<<dim3(16, 16, 3), 256, 0, stream>>>(Wq, Wk, Wv, WcatT);

    // ---- fused QKV projection: QKV[4096][3072] = xb @ Wcat^T + bcat ----
    gemm_nt<0, 128><<<dim3(24, 32), 256, 0, stream>>>(
        xb, WcatT, D_DIM, D_DIM, 3 * D_DIM, D_DIM,
        bcat, nullptr, QKVb, nullptr, nullptr);

    // ---- E = exp(mask * (Q K^T)); denom[row] = rowsum(E) via atomics ----
    const __bf16* Qb = QKVb;
    const __bf16* Kb = QKVb + D_DIM;
    gemm_nt<1, 128><<<dim3(32, 32), 256, 0, stream>>>(
        Qb, Kb, 3 * D_DIM, 3 * D_DIM, N_TOK, D_DIM,
        nullptr, mask, Eb, nullptr, denom);

    // ---- VsT[d][j] = V[j][d]/denom[j] (V strided in QKV buffer) ----
    scale_transpose<<<dim3(16, 64), 256, 0, stream>>>(QKVb + 2048, 3 * D_DIM, denom, VsT);

    // ---- out = E @ Vs : 128x64 tiles, grid 512 blocks, no split-K ----
    gemm_nt<2, 64><<<dim3(16, 32), 256, 0, stream>>>(
        Eb, VsT, N_TOK, N_TOK, D_DIM, N_TOK,
        nullptr, nullptr, nullptr, out, nullptr);
}

// Round 4
// 239.713 us; speedup vs baseline: 1.4599x; 1.0902x over previous
//
#include <hip/hip_runtime.h>
#include <hip/hip_bf16.h>

// ---------------------------------------------------------------------------
// AttentionLayer: out = quirky_softmax(mask * (Q K^T)) @ V
//   denom[j] = sum_k exp(mask[j,k]*S[j,k])  (row sums)
//   softmax[i,j] = E[i,j] / denom[j]        (column-indexed denom!)
//   => out = E @ (V scaled per-row by 1/denom)
// R3->R4: E + scaled-V stored in fp8 e4m3; out-GEMM in fp8 MFMA (BK=128).
// Denominator self-correction makes fp8 E error ~2e-5 in the output.
// ---------------------------------------------------------------------------

#define N_TOK 4096
#define D_DIM 1024
#define VS_SCALE 131072.0f        // 2^17: lifts V/denom (~7e-6) into fp8 range

typedef __bf16 bf16x8 __attribute__((ext_vector_type(8)));
typedef __bf16 bf16x4 __attribute__((ext_vector_type(4)));
typedef float  f32x4  __attribute__((ext_vector_type(4)));

typedef const __attribute__((address_space(1))) char g_char;
typedef __attribute__((address_space(3))) char lds_char;

__device__ inline unsigned char f32_to_fp8(float f) {
    return (unsigned char)(__builtin_amdgcn_cvt_pk_fp8_f32(f, f, 0, false) & 0xff);
}

// ---------------------------------------------------------------------------
// fp32 -> bf16 convert (blocks 0..4095) + bias concat (blocks 4096..4107)
// ---------------------------------------------------------------------------
__global__ void cvt_and_bias(const float* __restrict__ x, __bf16* __restrict__ xb,
                             const float* __restrict__ bq, const float* __restrict__ bk,
                             const float* __restrict__ bv, float* __restrict__ bcat) {
    int b = blockIdx.x;
    if (b < 4096) {
        int i = (b * 256 + threadIdx.x) * 4;
        float4 v = *(const float4*)(x + i);
        bf16x4 o;
        o.x = (__bf16)v.x; o.y = (__bf16)v.y;
        o.z = (__bf16)v.z; o.w = (__bf16)v.w;
        *(bf16x4*)(xb + i) = o;
    } else {
        int i = (b - 4096) * 256 + threadIdx.x;
        if (i < 1024) bcat[i] = bq[i];
        else if (i < 2048) bcat[i] = bk[i - 1024];
        else if (i < 3072) bcat[i] = bv[i - 2048];
    }
}

// ---------------------------------------------------------------------------
// Transpose three 1024x1024 fp32 W -> bf16 [out][in], concatenated
// ---------------------------------------------------------------------------
__global__ void transpose_w3(const float* __restrict__ Wq, const float* __restrict__ Wk,
                             const float* __restrict__ Wv, __bf16* __restrict__ outT) {
    const float* in = (blockIdx.z == 0) ? Wq : (blockIdx.z == 1) ? Wk : Wv;
    __bf16* oT = outT + (size_t)blockIdx.z * 1024 * 1024;
    __shared__ float t[64][65];
    const int c0 = blockIdx.x * 64, r0 = blockIdx.y * 64;
    const int tid = threadIdx.x;
#pragma unroll
    for (int k = 0; k < 16; k++) {
        int lin = tid + k * 256;
        int r = lin >> 6, c = lin & 63;
        t[r][c] = in[(size_t)(r0 + r) * 1024 + c0 + c];
    }
    __syncthreads();
#pragma unroll
    for (int k = 0; k < 16; k++) {
        int lin = tid + k * 256;
        int c = lin >> 6, r = lin & 63;
        oT[(size_t)(c0 + c) * 1024 + r0 + r] = (__bf16)t[r][c];
    }
}

// ---------------------------------------------------------------------------
// VsT[d][j] = fp8( VS_SCALE * V[j][d] / denom[j] ), V row stride ldv
// ---------------------------------------------------------------------------
__global__ void scale_transpose(const __bf16* __restrict__ V, int ldv,
                                const float* __restrict__ denom,
                                unsigned char* __restrict__ VT8) {
    __shared__ float t[64][65];
    __shared__ float rd[64];
    const int d0 = blockIdx.x * 64, j0 = blockIdx.y * 64;
    const int tid = threadIdx.x;
    if (tid < 64) rd[tid] = VS_SCALE / denom[j0 + tid];
    __syncthreads();
#pragma unroll
    for (int k = 0; k < 16; k++) {
        int lin = tid + k * 256;
        int j = lin >> 6, d = lin & 63;
        t[j][d] = (float)V[(size_t)(j0 + j) * ldv + d0 + d] * rd[j];
    }
    __syncthreads();
#pragma unroll
    for (int k = 0; k < 16; k++) {
        int lin = tid + k * 256;
        int d = lin >> 6, j = lin & 63;
        VT8[(size_t)(d0 + d) * N_TOK + j0 + j] = f32_to_fp8(t[j][d]);
    }
}

// ---------------------------------------------------------------------------
// NT GEMM (bf16): C = A * B^T, fp32 acc, BK=64, 128x128 tile, XOR-swizzled LDS.
// EPI 0: Cb = bf16(acc + bias[col])
// EPI 1: C8 = fp8(exp(mask[idx]*acc)); denom[row] += rowsum (atomic, pre-round)
// ---------------------------------------------------------------------------
template <int EPI>
__global__ __launch_bounds__(256, 2)
void gemm_nt(const __bf16* __restrict__ A, const __bf16* __restrict__ B,
             int lda, int ldb, int ldc, int K,
             const float* __restrict__ bias,
             const float* __restrict__ mask,
             __bf16* __restrict__ Cb, unsigned char* __restrict__ C8,
             float* __restrict__ denom) {
    __shared__ __bf16 lA[128 * 64];
    __shared__ __bf16 lB[128 * 64];

    const int tid  = threadIdx.x;
    const int wave = tid >> 6;
    const int lane = tid & 63;
    const int quad = lane >> 4;
    const int l16  = lane & 15;
    const int m0 = blockIdx.y * 128;
    const int n0 = blockIdx.x * 128;
    const int wr = (wave >> 1) * 64;
    const int wc = (wave & 1) * 64;

    // staging: LDS 16B-chunk p=c*256+tid holds global chunk ((p&7)^((p>>3)&7))
    // of row (p>>3); swizzle is pass-invariant (pass step 32 rows = 0 mod 8).
    const size_t lda_b = (size_t)lda * 2;
    const size_t ldb_b = (size_t)ldb * 2;
    const int tr = tid >> 3;
    const int ts = ((tid & 7) ^ (tr & 7)) * 16;
    const char* gA = (const char*)A + (size_t)(m0 + tr) * lda_b + ts;
    const char* gB = (const char*)B + (size_t)(n0 + tr) * ldb_b + ts;
    const size_t pstepA = (size_t)32 * lda_b;
    const size_t pstepB = (size_t)32 * ldb_b;

    lds_char* lAp = (lds_char*)(void*)lA + wave * 1024;
    lds_char* lBp = (lds_char*)(void*)lB + wave * 1024;

    // read addrs: frag chunk = ks*4+quad, swizzled pos = chunk^(l16&7)
    const int l7 = l16 & 7;
    const int rdA0 = ((wr + l16) * 128 + ((quad ^ l7) * 16)) >> 1;
    const int rdA1 = ((wr + l16) * 128 + (((4 + quad) ^ l7) * 16)) >> 1;
    const int rdB0 = ((wc + l16) * 128 + ((quad ^ l7) * 16)) >> 1;
    const int rdB1 = ((wc + l16) * 128 + (((4 + quad) ^ l7) * 16)) >> 1;

    f32x4 acc[4][4];
#pragma unroll
    for (int i = 0; i < 4; i++)
#pragma unroll
        for (int j = 0; j < 4; j++) acc[i][j] = (f32x4){0.f, 0.f, 0.f, 0.f};

    for (int kt = 0; kt < K; kt += 64) {
#pragma unroll
        for (int c = 0; c < 4; c++)
            __builtin_amdgcn_global_load_lds((g_char*)(gA + c * pstepA),
                                             lAp + c * 4096, 16, 0, 0);
#pragma unroll
        for (int c = 0; c < 4; c++)
            __builtin_amdgcn_global_load_lds((g_char*)(gB + c * pstepB),
                                             lBp + c * 4096, 16, 0, 0);
        gA += 128;
        gB += 128;
        __syncthreads();

        bf16x8 af[4], bfr[4];
#pragma unroll
        for (int i = 0; i < 4; i++) af[i] = *(const bf16x8*)&lA[rdA0 + i * 1024];
#pragma unroll
        for (int j = 0; j < 4; j++) bfr[j] = *(const bf16x8*)&lB[rdB0 + j * 1024];
#pragma unroll
        for (int i = 0; i < 4; i++)
#pragma unroll
            for (int j = 0; j < 4; j++)
                acc[i][j] = __builtin_amdgcn_mfma_f32_16x16x32_bf16(
                    af[i], bfr[j], acc[i][j], 0, 0, 0);
#pragma unroll
        for (int i = 0; i < 4; i++) af[i] = *(const bf16x8*)&lA[rdA1 + i * 1024];
#pragma unroll
        for (int j = 0; j < 4; j++) bfr[j] = *(const bf16x8*)&lB[rdB1 + j * 1024];
#pragma unroll
        for (int i = 0; i < 4; i++)
#pragma unroll
            for (int j = 0; j < 4; j++)
                acc[i][j] = __builtin_amdgcn_mfma_f32_16x16x32_bf16(
                    af[i], bfr[j], acc[i][j], 0, 0, 0);
        __syncthreads();
    }

    // epilogue: C/D layout col=lane&15, row=quad*4+reg
#pragma unroll
    for (int i = 0; i < 4; i++) {
        const int rbase = m0 + wr + i * 16 + quad * 4;
        f32x4 rs = (f32x4){0.f, 0.f, 0.f, 0.f};
#pragma unroll
        for (int j = 0; j < 4; j++) {
            const int col = n0 + wc + j * 16 + l16;
            f32x4 v = acc[i][j];
            if (EPI == 0) {
                const float bb = bias[col];
#pragma unroll
                for (int r = 0; r < 4; r++)
                    Cb[(size_t)(rbase + r) * ldc + col] = (__bf16)(v[r] + bb);
            } else {
#pragma unroll
                for (int r = 0; r < 4; r++) {
                    size_t idx = (size_t)(rbase + r) * ldc + col;
                    float e = __expf(mask[idx] * v[r]);
                    C8[idx] = f32_to_fp8(e);
                    rs[r] += e;   // pre-round sum: bias contribution ~5e-6, negligible
                }
            }
        }
        if (EPI == 1) {
#pragma unroll
            for (int m = 1; m < 16; m <<= 1) {
#pragma unroll
                for (int r = 0; r < 4; r++) rs[r] += __shfl_xor(rs[r], m, 64);
            }
            if (l16 == 0) {
#pragma unroll
                for (int r = 0; r < 4; r++) atomicAdd(&denom[rbase + r], rs[r]);
            }
        }
    }
}

// ---------------------------------------------------------------------------
// out GEMM (fp8): C[4096][1024] = E[4096][4096] * VsT[1024][4096]^T, BK=128.
// 128x64 tile, 4 waves each 64x32 (4x2 frags). LDS byte layout identical to
// bf16 BK=64 swizzle (rows = 128 B = 8 x 16B chunks, chunk q at q^(r&7)).
// Per MFMA (16x16x32 fp8): lane holds 8 B at row byte offset kstep*32+quad*8.
// ---------------------------------------------------------------------------
__global__ __launch_bounds__(256, 2)
void gemm_out_fp8(const unsigned char* __restrict__ A,
                  const unsigned char* __restrict__ B,
                  float* __restrict__ C) {
    __shared__ unsigned char lA[128 * 128];
    __shared__ unsigned char lB[64 * 128];

    const int tid  = threadIdx.x;
    const int wave = tid >> 6;
    const int lane = tid & 63;
    const int quad = lane >> 4;
    const int l16  = lane & 15;
    const int m0 = blockIdx.y * 128;
    const int n0 = blockIdx.x * 64;
    const int wr = (wave >> 1) * 64;
    const int wc = (wave & 1) * 32;

    const int tr = tid >> 3;
    const int ts = ((tid & 7) ^ (tr & 7)) * 16;
    const char* gA = (const char*)A + (size_t)(m0 + tr) * N_TOK + ts;
    const char* gB = (const char*)B + (size_t)(n0 + tr) * N_TOK + ts;
    const size_t pstep = (size_t)32 * N_TOK;

    lds_char* lAp = (lds_char*)(void*)lA + wave * 1024;
    lds_char* lBp = (lds_char*)(void*)lB + wave * 1024;

    // read addr: row*128 + ((kstep*2 + (quad>>1)) ^ (l16&7))*16 + (quad&1)*8
    const int l7 = l16 & 7;
    const int qhi = quad >> 1, qlo = (quad & 1) * 8;
    int rdA[4], rdB[4];
#pragma unroll
    for (int k = 0; k < 4; k++) {
        rdA[k] = ((k * 2 + qhi) ^ l7) * 16 + qlo;   // add row*128 per-frag
        rdB[k] = rdA[k];
    }

    f32x4 acc[4][2];
#pragma unroll
    for (int i = 0; i < 4; i++)
#pragma unroll
        for (int j = 0; j < 2; j++) acc[i][j] = (f32x4){0.f, 0.f, 0.f, 0.f};

    for (int kt = 0; kt < N_TOK; kt += 128) {
#pragma unroll
        for (int c = 0; c < 4; c++)
            __builtin_amdgcn_global_load_lds((g_char*)(gA + c * pstep),
                                             lAp + c * 4096, 16, 0, 0);
#pragma unroll
        for (int c = 0; c < 2; c++)
            __builtin_amdgcn_global_load_lds((g_char*)(gB + c * pstep),
                                             lBp + c * 4096, 16, 0, 0);
        gA += 128;
        gB += 128;
        __syncthreads();

#pragma unroll
        for (int k = 0; k < 4; k++) {
            long a[4], b[2];
#pragma unroll
            for (int i = 0; i < 4; i++)
                a[i] = *(const long*)&lA[(wr + i * 16 + l16) * 128 + rdA[k]];
#pragma unroll
            for (int j = 0; j < 2; j++)
                b[j] = *(const long*)&lB[(wc + j * 16 + l16) * 128 + rdB[k]];
#pragma unroll
            for (int i = 0; i < 4; i++)
#pragma unroll
                for (int j = 0; j < 2; j++)
                    acc[i][j] = __builtin_amdgcn_mfma_f32_16x16x32_fp8_fp8(
                        a[i], b[j], acc[i][j], 0, 0, 0);
        }
        __syncthreads();
    }

#pragma unroll
    for (int i = 0; i < 4; i++) {
#pragma unroll
        for (int j = 0; j < 2; j++) {
            const int col   = n0 + wc + j * 16 + l16;
            const int rbase = m0 + wr + i * 16 + quad * 4;
            f32x4 v = acc[i][j];
#pragma unroll
            for (int r = 0; r < 4; r++)
                C[(size_t)(rbase + r) * D_DIM + col] = v[r] * (1.0f / VS_SCALE);
        }
    }
}

// ---------------------------------------------------------------------------
extern "C" void kernel_launch(void* const* d_in, const int* in_sizes, int n_in,
                              void* d_out, int out_size, void* d_ws, size_t ws_size,
                              hipStream_t stream) {
    const float* x    = (const float*)d_in[0];
    const float* mask = (const float*)d_in[1];
    const float* Wq   = (const float*)d_in[2];
    const float* bq   = (const float*)d_in[3];
    const float* Wk   = (const float*)d_in[4];
    const float* bk   = (const float*)d_in[5];
    const float* Wv   = (const float*)d_in[6];
    const float* bv   = (const float*)d_in[7];
    float* out = (float*)d_out;
    char* ws = (char*)d_ws;

    const size_t MB = 1024 * 1024;
    unsigned char* E8   = (unsigned char*)(ws + 0 * MB);   // 16 MB [4096][4096] fp8
    __bf16* QKVb  = (__bf16*)(ws + 16 * MB);               // 24 MB [4096][3072]
    __bf16* xb    = (__bf16*)(ws + 40 * MB);               // 8 MB [4096][1024]
    unsigned char* VsT8 = (unsigned char*)xb;              // 4 MB (reuses dead xb)
    __bf16* WcatT = (__bf16*)(ws + 48 * MB);               // 6 MB [3072][1024]
    float*  bcat  = (float*)(ws + 54 * MB);                // 12 KB
    float*  denom = (float*)(ws + 54 * MB + 64 * 1024);    // 16 KB

    hipMemsetAsync(denom, 0, N_TOK * sizeof(float), stream);

    // ---- prep ----
    cvt_and_bias<<<4096 + 12, 256, 0, stream>>>(x, xb, bq, bk, bv, bcat);
    transpose_w3<<<dim3(16, 16, 3), 256, 0, stream>>>(Wq, Wk, Wv, WcatT);

    // ---- fused QKV projection ----
    gemm_nt<0><<<dim3(24, 32), 256, 0, stream>>>(
        xb, WcatT, D_DIM, D_DIM, 3 * D_DIM, D_DIM,
        bcat, nullptr, QKVb, nullptr, nullptr);

    // ---- E = exp(mask * (Q K^T)) -> fp8; denom[row] += rowsum ----
    const __bf16* Qb = QKVb;
    const __bf16* Kb = QKVb + D_DIM;
    gemm_nt<1><<<dim3(32, 32), 256, 0, stream>>>(
        Qb, Kb, 3 * D_DIM, 3 * D_DIM, N_TOK, D_DIM,
        nullptr, mask, nullptr, E8, denom);

    // ---- VsT8[d][j] = fp8(VS_SCALE * V[j][d] / denom[j]) ----
    scale_transpose<<<dim3(16, 64), 256, 0, stream>>>(QKVb + 2048, 3 * D_DIM, denom, VsT8);

    // ---- out = (E8 @ VsT8^T) / VS_SCALE ----
    gemm_out_fp8<<<dim3(16, 32), 256, 0, stream>>>(E8, VsT8, out);
}